// Round 9
// baseline (141.598 us; speedup 1.0000x reference)
//
#include <hip/hip_runtime.h>
#include <hip/hip_bf16.h>

#define D 128  // D_IN == D_OUT == 128

typedef __attribute__((ext_vector_type(8))) short short8v;   // 8 bf16 (4 VGPR)
typedef __attribute__((ext_vector_type(4))) float float4v;   // MFMA acc

__device__ __forceinline__ unsigned short f2bf(float f) {
  union { float f; unsigned int u; } v; v.f = f;
  unsigned int r = v.u + 0x7fffu + ((v.u >> 16) & 1u);  // RNE
  return (unsigned short)(r >> 16);
}
// packed pair conversion -> v_cvt_pk_bf16_f32 (RNE)
__device__ __forceinline__ unsigned int pkbf(float lo, float hi) {
  float2 f; f.x = lo; f.y = hi;
  __hip_bfloat162 v = __float22bfloat162_rn(f);
  union { __hip_bfloat162 b; unsigned int u; } c; c.b = v;
  return c.u;
}
__device__ __forceinline__ float bflo(unsigned int u) {
  union { unsigned int v; float f; } c; c.v = u << 16; return c.f;
}
__device__ __forceinline__ float bfhi(unsigned int u) {
  union { unsigned int v; float f; } c; c.v = u & 0xffff0000u; return c.f;
}

// == prep: Wt[n][k]=bf16(W[k][n]); em_bf=bf16(eemb); zero counts+sentinels ==
__global__ __launch_bounds__(256) void prep_kernel(
    const float* __restrict__ W, const float* __restrict__ eemb,
    unsigned short* __restrict__ Wt, unsigned short* __restrict__ em_bf,
    unsigned short* __restrict__ h_bf, int* __restrict__ counts,
    int n_nodes) {
  int i = blockIdx.x * 256 + threadIdx.x;
  if (i < D * D) Wt[i] = f2bf(W[(i & 127) * D + (i >> 7)]);      // transpose
  if (i < 64 * D) em_bf[i] = f2bf(eemb[i]);
  if (i < 64) ((unsigned int*)(h_bf + (size_t)n_nodes * D))[i] = 0u;
  if (i >= 64 && i < 128) ((unsigned int*)(em_bf + 64 * D))[i - 64] = 0u;
  if (i < n_nodes) counts[i] = 0;  // replaces hipMemsetAsync
}

// ================= GEMM: LDS-free, barrier-free, swapped MFMA ==============
// Block 256 = 4 independent waves; wave = 16 nodes x 128 cols.
// B-frags (X) load straight from global: lane (m,q) reads
// nf[node_m][kc*32+q*8..+8] -- the 4 q-groups tile each row's 128B span, so
// coalescing is exact and nf is fetched once. A-frags (Wt, 32KB, L1-hot)
// reload per nt (4 live). Hist atomics issue after the epilogue.
__global__ __launch_bounds__(256) void gemm_h_kernel(
    const float* __restrict__ nf, const unsigned short* __restrict__ Wt,
    const float* __restrict__ b, unsigned short* __restrict__ h_bf,
    const int* __restrict__ eidx_tgt, int* __restrict__ counts,
    int n_nodes, int n_edges, int epb) {
  const int tid = threadIdx.x;
  const int wv = tid >> 6;
  const int ln = tid & 63;
  const int m = ln & 15;   // node within the wave's 16
  const int q = ln >> 4;   // k-quarter / output row-quarter
  const int node = blockIdx.x * 64 + wv * 16 + m;
  const int row = node < n_nodes ? node : n_nodes - 1;  // clamped load row
  const float* xrow = nf + (size_t)row * D;

  // ---- B fragments: 8 dwordx4 loads + 16 cvt_pk ----
  short8v bfrag[4];
  #pragma unroll
  for (int kc = 0; kc < 4; ++kc) {
    const float4 x0 = *(const float4*)(xrow + kc * 32 + q * 8);
    const float4 x1 = *(const float4*)(xrow + kc * 32 + q * 8 + 4);
    union { unsigned int u[4]; short8v s; } cv;
    cv.u[0] = pkbf(x0.x, x0.y);
    cv.u[1] = pkbf(x0.z, x0.w);
    cv.u[2] = pkbf(x1.x, x1.y);
    cv.u[3] = pkbf(x1.z, x1.w);
    bfrag[kc] = cv.s;
  }

  // ---- 8 col-tiles x 4 k-chunks of MFMA; A-frags reload per tile ----
  float4v acc[8] = {};
  #pragma unroll
  for (int nt = 0; nt < 8; ++nt) {
    const unsigned short* wrow = Wt + (nt * 16 + m) * D + q * 8;
    const short8v a0 = *(const short8v*)(wrow);
    const short8v a1 = *(const short8v*)(wrow + 32);
    const short8v a2 = *(const short8v*)(wrow + 64);
    const short8v a3 = *(const short8v*)(wrow + 96);
    acc[nt] = __builtin_amdgcn_mfma_f32_16x16x32_bf16(a0, bfrag[0], acc[nt], 0, 0, 0);
    acc[nt] = __builtin_amdgcn_mfma_f32_16x16x32_bf16(a1, bfrag[1], acc[nt], 0, 0, 0);
    acc[nt] = __builtin_amdgcn_mfma_f32_16x16x32_bf16(a2, bfrag[2], acc[nt], 0, 0, 0);
    acc[nt] = __builtin_amdgcn_mfma_f32_16x16x32_bf16(a3, bfrag[3], acc[nt], 0, 0, 0);
  }

  // ---- epilogue: +bias, cvt_pk, 8B stores (lane owns node's cols q*4..) ----
  if (node < n_nodes) {
    unsigned short* orow = h_bf + (size_t)node * D + q * 4;
    #pragma unroll
    for (int nt = 0; nt < 8; ++nt) {
      const float4 bv = *(const float4*)&b[nt * 16 + q * 4];
      uint2 val;
      val.x = pkbf(acc[nt][0] + bv.x, acc[nt][1] + bv.y);
      val.y = pkbf(acc[nt][2] + bv.z, acc[nt][3] + bv.w);
      *(uint2*)(orow + nt * 16) = val;
    }
  }

  // ---- fused histogram (issued last: no younger loads wait on it) ----
  const int ebase = blockIdx.x * epb;
  int eend = ebase + epb;
  if (eend > n_edges) eend = n_edges;
  for (int e = ebase + tid; e < eend; e += 256)
    atomicAdd(&counts[eidx_tgt[e]], 1);
}

// ============================ scan =========================================
// pass 1: per-block (1024 elems) local exclusive scan; blockSums[b] = total
__global__ __launch_bounds__(256) void scan1_kernel(
    const int* __restrict__ counts, int* __restrict__ offsets,
    int* __restrict__ blockSums, int n) {
  __shared__ int lds[256];
  const int tid = threadIdx.x;
  const int base = blockIdx.x * 1024 + tid * 4;
  int v[4];
  #pragma unroll
  for (int k = 0; k < 4; ++k) v[k] = (base + k < n) ? counts[base + k] : 0;
  int s = v[0] + v[1] + v[2] + v[3];
  lds[tid] = s;
  for (int off = 1; off < 256; off <<= 1) {
    __syncthreads();
    int t = (tid >= off) ? lds[tid - off] : 0;
    __syncthreads();
    lds[tid] += t;
  }
  __syncthreads();
  int run = lds[tid] - s;
  #pragma unroll
  for (int k = 0; k < 4; ++k) {
    if (base + k < n) offsets[base + k] = run;
    run += v[k];
  }
  if (tid == 255) blockSums[blockIdx.x] = lds[255];
}

// pass 2 (fused scan2+scan3): each block reduces blockSums[0..bid-1] in LDS,
// adds to its 1024 offsets, copies to cursor. Requires nb <= 256.
__global__ __launch_bounds__(256) void scan23_kernel(
    int* __restrict__ offsets, int* __restrict__ cursor,
    const int* __restrict__ blockSums, int nb, int n, int n_edges) {
  __shared__ int lds[256];
  const int tid = threadIdx.x;
  const int bid = blockIdx.x;
  lds[tid] = (tid < bid && tid < nb) ? blockSums[tid] : 0;
  __syncthreads();
  #pragma unroll
  for (int off = 128; off > 0; off >>= 1) {
    if (tid < off) lds[tid] += lds[tid + off];
    __syncthreads();
  }
  const int add = lds[0];
  const int base = bid * 1024 + tid * 4;
  #pragma unroll
  for (int k = 0; k < 4; ++k) {
    int i = base + k;
    if (i < n) {
      int o = offsets[i] + add;
      offsets[i] = o;
      cursor[i] = o;
    }
  }
  if (bid == 0 && tid == 0) offsets[n] = n_edges;
}

// ================== scatter: 4 edges/thread via int4 =======================
__global__ __launch_bounds__(256) void scatter_kernel(
    const int* __restrict__ eidx, const int* __restrict__ etype,
    int* __restrict__ cursor, unsigned int* __restrict__ packed, int n_edges) {
  const int e0 = (blockIdx.x * 256 + threadIdx.x) * 4;
  if (e0 + 3 < n_edges) {
    const int4 s4 = *(const int4*)&eidx[e0];
    const int4 t4 = *(const int4*)&eidx[n_edges + e0];
    const int4 y4 = *(const int4*)&etype[e0];
    int pos;
    pos = atomicAdd(&cursor[t4.x], 1);
    packed[pos] = (unsigned int)s4.x | ((unsigned int)y4.x << 17);
    pos = atomicAdd(&cursor[t4.y], 1);
    packed[pos] = (unsigned int)s4.y | ((unsigned int)y4.y << 17);
    pos = atomicAdd(&cursor[t4.z], 1);
    packed[pos] = (unsigned int)s4.z | ((unsigned int)y4.z << 17);
    pos = atomicAdd(&cursor[t4.w], 1);
    packed[pos] = (unsigned int)s4.w | ((unsigned int)y4.w << 17);
  } else {
    for (int e = e0; e < n_edges; ++e) {
      const int pos = atomicAdd(&cursor[eidx[n_edges + e]], 1);
      packed[pos] = (unsigned int)eidx[e] | ((unsigned int)etype[e] << 17);
    }
  }
}

// ================ aggregate: 2 nodes per wave, 4-deep pipeline =============
// out[n] = relu(h[n] + sum_{edges->n} (h[src] + em[etype])); h,em bf16.
// Lane covers 4 dims via uint2 (8B); invalid edges -> zero rows (L1-hot).
__global__ __launch_bounds__(256) void aggregate_kernel(
    const int* __restrict__ offsets, const unsigned int* __restrict__ packed,
    const uint2* __restrict__ e4, const uint2* __restrict__ h4,
    float* __restrict__ out, int n_nodes, int n_edges, unsigned int zero_p) {
  const int gid = blockIdx.x * 256 + threadIdx.x;
  const int lane = threadIdx.x & 63;
  const int half = lane >> 5;
  const int sl = lane & 31;
  const int n = (gid >> 6) * 2 + half;
  if (n >= n_nodes) return;

  const uint2 sb = h4[(size_t)n * 32 + sl];  // self (4 bf16)
  float a0 = bflo(sb.x), a1 = bfhi(sb.x), a2 = bflo(sb.y), a3 = bfhi(sb.y);
  float c0 = 0.f, c1 = 0.f, c2 = 0.f, c3 = 0.f;

  int j = offsets[n];
  const int end = offsets[n + 1];
  int trips = (end - j + 3) >> 2;
  int to = __shfl_xor(trips, 32);
  const int T = trips > to ? trips : to;
  const int emax = n_edges - 1;

  for (int t = 0; t < T; ++t, j += 4) {
    const int j1 = j + 1, j2 = j + 2, j3 = j + 3;
    unsigned int p0 = packed[j  <= emax ? j  : emax];
    unsigned int p1 = packed[j1 <= emax ? j1 : emax];
    unsigned int p2 = packed[j2 <= emax ? j2 : emax];
    unsigned int p3 = packed[j3 <= emax ? j3 : emax];
    p0 = (j  < end) ? p0 : zero_p;
    p1 = (j1 < end) ? p1 : zero_p;
    p2 = (j2 < end) ? p2 : zero_p;
    p3 = (j3 < end) ? p3 : zero_p;
    const uint2 g0 = h4[(size_t)(p0 & 0x1FFFFu) * 32 + sl];
    const uint2 g1 = h4[(size_t)(p1 & 0x1FFFFu) * 32 + sl];
    const uint2 g2 = h4[(size_t)(p2 & 0x1FFFFu) * 32 + sl];
    const uint2 g3 = h4[(size_t)(p3 & 0x1FFFFu) * 32 + sl];
    const uint2 e0 = e4[(p0 >> 17) * 32 + sl];
    const uint2 e1 = e4[(p1 >> 17) * 32 + sl];
    const uint2 e2 = e4[(p2 >> 17) * 32 + sl];
    const uint2 e3 = e4[(p3 >> 17) * 32 + sl];
    a0 += bflo(g0.x) + bflo(e0.x); a1 += bfhi(g0.x) + bfhi(e0.x);
    a2 += bflo(g0.y) + bflo(e0.y); a3 += bfhi(g0.y) + bfhi(e0.y);
    c0 += bflo(g1.x) + bflo(e1.x); c1 += bfhi(g1.x) + bfhi(e1.x);
    c2 += bflo(g1.y) + bflo(e1.y); c3 += bfhi(g1.y) + bfhi(e1.y);
    a0 += bflo(g2.x) + bflo(e2.x); a1 += bfhi(g2.x) + bfhi(e2.x);
    a2 += bflo(g2.y) + bflo(e2.y); a3 += bfhi(g2.y) + bfhi(e2.y);
    c0 += bflo(g3.x) + bflo(e3.x); c1 += bfhi(g3.x) + bfhi(e3.x);
    c2 += bflo(g3.y) + bflo(e3.y); c3 += bfhi(g3.y) + bfhi(e3.y);
  }

  float4 r;
  r.x = fmaxf(a0 + c0, 0.f);
  r.y = fmaxf(a1 + c1, 0.f);
  r.z = fmaxf(a2 + c2, 0.f);
  r.w = fmaxf(a3 + c3, 0.f);
  ((float4*)out)[(size_t)n * 32 + sl] = r;
}

// ===========================================================================
extern "C" void kernel_launch(void* const* d_in, const int* in_sizes, int n_in,
                              void* d_out, int out_size, void* d_ws,
                              size_t ws_size, hipStream_t stream) {
  const float* nf   = (const float*)d_in[0];  // (N, 128) f32
  const int*   eidx = (const int*)d_in[1];    // (2, E) int
  const int*   etyp = (const int*)d_in[2];    // (E,) int
  const float* eemb = (const float*)d_in[3];  // (64, 128) f32
  const float* W    = (const float*)d_in[4];  // (128, 128) f32
  const float* b    = (const float*)d_in[5];  // (128,) f32

  const int n_nodes = in_sizes[0] / D;  // 100000
  const int n_edges = in_sizes[2];      // 625000

  float* out = (float*)d_out;

  // workspace layout (~29.5 MB); 16B alignment maintained
  char* base = (char*)d_ws;
  unsigned short* Wt = (unsigned short*)base;                  // 32 KB
  unsigned short* em_bf = (unsigned short*)(base + 32768);     // 65 rows
  unsigned short* h_bf = (unsigned short*)(base + 65536);      // (N+1)*128 bf16
  char* tail = base + 65536 + (size_t)(n_nodes + 1) * D * 2;
  int* counts = (int*)tail;
  int* offsets = counts + n_nodes;
  int* cursor = offsets + (n_nodes + 1);
  int* blockSums = cursor + n_nodes;
  unsigned int* packed = (unsigned int*)(blockSums + 1024);    // E uints

  const int nb = (n_nodes + 1023) / 1024;        // 98 scan blocks (<=256)
  const int gemmBlocks = (n_nodes + 63) / 64;    // 1563
  const int epb = (n_edges + gemmBlocks - 1) / gemmBlocks;  // 400

  // 1) prep: Wt transpose+cast, em cast, zero counts + sentinel rows
  prep_kernel<<<(n_nodes + 255) / 256, 256, 0, stream>>>(W, eemb, Wt, em_bf,
                                                         h_bf, counts, n_nodes);

  // 2) GEMM h_bf = bf16(nf @ W + b) + fused histogram (LDS-free)
  gemm_h_kernel<<<gemmBlocks, 256, 0, stream>>>(
      nf, Wt, b, h_bf, eidx + n_edges, counts, n_nodes, n_edges, epb);

  // 3) scan (2 kernels)
  scan1_kernel<<<nb, 256, 0, stream>>>(counts, offsets, blockSums, n_nodes);
  scan23_kernel<<<nb, 256, 0, stream>>>(offsets, cursor, blockSums, nb,
                                        n_nodes, n_edges);

  // 4) scatter packed (src|etype) by target
  scatter_kernel<<<(n_edges + 1023) / 1024, 256, 0, stream>>>(
      eidx, etyp, cursor, packed, n_edges);

  // 5) aggregate + self + ReLU (2 nodes/wave, 4-deep)
  const unsigned int zero_p = (unsigned int)n_nodes | (64u << 17);
  const int aggBlocks = (n_nodes + 7) / 8;  // 8 nodes per 256-thread block
  aggregate_kernel<<<aggBlocks, 256, 0, stream>>>(
      offsets, packed, (const uint2*)em_bf, (const uint2*)h_bf, out, n_nodes,
      n_edges, zero_p);
}

// Round 10
// 138.061 us; speedup vs baseline: 1.0256x; 1.0256x over previous
//
#include <hip/hip_runtime.h>
#include <hip/hip_bf16.h>

#define D 128  // D_IN == D_OUT == 128

typedef __attribute__((ext_vector_type(8))) short short8v;   // 8 bf16 (4 VGPR)
typedef __attribute__((ext_vector_type(4))) float float4v;   // MFMA acc

__device__ __forceinline__ unsigned short f2bf(float f) {
  union { float f; unsigned int u; } v; v.f = f;
  unsigned int r = v.u + 0x7fffu + ((v.u >> 16) & 1u);  // RNE
  return (unsigned short)(r >> 16);
}
// packed pair conversion -> v_cvt_pk_bf16_f32 (RNE)
__device__ __forceinline__ unsigned int pkbf(float lo, float hi) {
  float2 f; f.x = lo; f.y = hi;
  __hip_bfloat162 v = __float22bfloat162_rn(f);
  union { __hip_bfloat162 b; unsigned int u; } c; c.b = v;
  return c.u;
}
__device__ __forceinline__ float bflo(unsigned int u) {
  union { unsigned int v; float f; } c; c.v = u << 16; return c.f;
}
__device__ __forceinline__ float bfhi(unsigned int u) {
  union { unsigned int v; float f; } c; c.v = u & 0xffff0000u; return c.f;
}

// == prep: Wt[n][k]=bf16(W[k][n]); em_bf=bf16(eemb); zero counts+sentinels ==
__global__ __launch_bounds__(256) void prep_kernel(
    const float* __restrict__ W, const float* __restrict__ eemb,
    unsigned short* __restrict__ Wt, unsigned short* __restrict__ em_bf,
    unsigned short* __restrict__ h_bf, int* __restrict__ counts,
    int n_nodes) {
  int i = blockIdx.x * 256 + threadIdx.x;
  if (i < D * D) Wt[i] = f2bf(W[(i & 127) * D + (i >> 7)]);      // transpose
  if (i < 64 * D) em_bf[i] = f2bf(eemb[i]);
  if (i < 64) ((unsigned int*)(h_bf + (size_t)n_nodes * D))[i] = 0u;
  if (i >= 64 && i < 128) ((unsigned int*)(em_bf + 64 * D))[i - 64] = 0u;
  if (i < n_nodes) counts[i] = 0;  // replaces hipMemsetAsync
}

// ================= GEMM: LDS-free, barrier-free, pipelined =================
// Block 256 = 4 independent waves; wave = 16 nodes x 128 cols.
// Fix vs R9 (1.25 TB/s latency-bound): (1) ALL 8 x-loads issued before any
// cvt (8 outstanding HBM loads/lane); (2) A-frags 2-stage prefetch (nt+1
// loads issued before nt's MFMAs); (3) launch_bounds(,4) -> ~128 VGPR budget.
__global__ __launch_bounds__(256, 4) void gemm_h_kernel(
    const float* __restrict__ nf, const unsigned short* __restrict__ Wt,
    const float* __restrict__ b, unsigned short* __restrict__ h_bf,
    const int* __restrict__ eidx_tgt, int* __restrict__ counts,
    int n_nodes, int n_edges, int epb) {
  const int tid = threadIdx.x;
  const int wv = tid >> 6;
  const int ln = tid & 63;
  const int m = ln & 15;   // node within the wave's 16
  const int q = ln >> 4;   // k-quarter / output row-quarter
  const int node = blockIdx.x * 64 + wv * 16 + m;
  const int row = node < n_nodes ? node : n_nodes - 1;  // clamped load row
  const float4* xr4 = (const float4*)(nf + (size_t)row * D);

  // ---- B fragments: issue ALL 8 dwordx4 loads, THEN convert ----
  float4 xv[8];
  #pragma unroll
  for (int kc = 0; kc < 4; ++kc) {
    xv[kc * 2]     = xr4[kc * 8 + q * 2];
    xv[kc * 2 + 1] = xr4[kc * 8 + q * 2 + 1];
  }
  short8v bfrag[4];
  #pragma unroll
  for (int kc = 0; kc < 4; ++kc) {
    union { unsigned int u[4]; short8v s; } cv;
    cv.u[0] = pkbf(xv[kc * 2].x, xv[kc * 2].y);
    cv.u[1] = pkbf(xv[kc * 2].z, xv[kc * 2].w);
    cv.u[2] = pkbf(xv[kc * 2 + 1].x, xv[kc * 2 + 1].y);
    cv.u[3] = pkbf(xv[kc * 2 + 1].z, xv[kc * 2 + 1].w);
    bfrag[kc] = cv.s;
  }

  // ---- 8 col-tiles x 4 k-chunks; A-frags 2-stage register pipeline ----
  const unsigned short* wbase = Wt + m * D + q * 8;  // + nt*16*D per tile
  short8v aC[4], aN[4];
  #pragma unroll
  for (int kc = 0; kc < 4; ++kc) aC[kc] = *(const short8v*)(wbase + kc * 32);

  float4v acc[8] = {};
  #pragma unroll
  for (int nt = 0; nt < 8; ++nt) {
    if (nt < 7) {
      const unsigned short* wn = wbase + (nt + 1) * 16 * D;
      #pragma unroll
      for (int kc = 0; kc < 4; ++kc) aN[kc] = *(const short8v*)(wn + kc * 32);
    }
    #pragma unroll
    for (int kc = 0; kc < 4; ++kc)
      acc[nt] = __builtin_amdgcn_mfma_f32_16x16x32_bf16(aC[kc], bfrag[kc],
                                                        acc[nt], 0, 0, 0);
    #pragma unroll
    for (int kc = 0; kc < 4; ++kc) aC[kc] = aN[kc];
  }

  // ---- epilogue: +bias, cvt_pk, 8B stores (lane owns node's cols q*4..) ----
  if (node < n_nodes) {
    unsigned short* orow = h_bf + (size_t)node * D + q * 4;
    #pragma unroll
    for (int nt = 0; nt < 8; ++nt) {
      const float4 bv = *(const float4*)&b[nt * 16 + q * 4];
      uint2 val;
      val.x = pkbf(acc[nt][0] + bv.x, acc[nt][1] + bv.y);
      val.y = pkbf(acc[nt][2] + bv.z, acc[nt][3] + bv.w);
      *(uint2*)(orow + nt * 16) = val;
    }
  }

  // ---- fused histogram (issued last: stores need no waits) ----
  const int ebase = blockIdx.x * epb;
  int eend = ebase + epb;
  if (eend > n_edges) eend = n_edges;
  for (int e = ebase + tid; e < eend; e += 256)
    atomicAdd(&counts[eidx_tgt[e]], 1);
}

// ============================ scan =========================================
// pass 1: per-block (1024 elems) local exclusive scan; blockSums[b] = total
__global__ __launch_bounds__(256) void scan1_kernel(
    const int* __restrict__ counts, int* __restrict__ offsets,
    int* __restrict__ blockSums, int n) {
  __shared__ int lds[256];
  const int tid = threadIdx.x;
  const int base = blockIdx.x * 1024 + tid * 4;
  int v[4];
  #pragma unroll
  for (int k = 0; k < 4; ++k) v[k] = (base + k < n) ? counts[base + k] : 0;
  int s = v[0] + v[1] + v[2] + v[3];
  lds[tid] = s;
  for (int off = 1; off < 256; off <<= 1) {
    __syncthreads();
    int t = (tid >= off) ? lds[tid - off] : 0;
    __syncthreads();
    lds[tid] += t;
  }
  __syncthreads();
  int run = lds[tid] - s;
  #pragma unroll
  for (int k = 0; k < 4; ++k) {
    if (base + k < n) offsets[base + k] = run;
    run += v[k];
  }
  if (tid == 255) blockSums[blockIdx.x] = lds[255];
}

// pass 2 (fused scan2+scan3): each block reduces blockSums[0..bid-1] in LDS,
// adds to its 1024 offsets, copies to cursor. Requires nb <= 256.
__global__ __launch_bounds__(256) void scan23_kernel(
    int* __restrict__ offsets, int* __restrict__ cursor,
    const int* __restrict__ blockSums, int nb, int n, int n_edges) {
  __shared__ int lds[256];
  const int tid = threadIdx.x;
  const int bid = blockIdx.x;
  lds[tid] = (tid < bid && tid < nb) ? blockSums[tid] : 0;
  __syncthreads();
  #pragma unroll
  for (int off = 128; off > 0; off >>= 1) {
    if (tid < off) lds[tid] += lds[tid + off];
    __syncthreads();
  }
  const int add = lds[0];
  const int base = bid * 1024 + tid * 4;
  #pragma unroll
  for (int k = 0; k < 4; ++k) {
    int i = base + k;
    if (i < n) {
      int o = offsets[i] + add;
      offsets[i] = o;
      cursor[i] = o;
    }
  }
  if (bid == 0 && tid == 0) offsets[n] = n_edges;
}

// ================== scatter: 4 edges/thread via int4 =======================
__global__ __launch_bounds__(256) void scatter_kernel(
    const int* __restrict__ eidx, const int* __restrict__ etype,
    int* __restrict__ cursor, unsigned int* __restrict__ packed, int n_edges) {
  const int e0 = (blockIdx.x * 256 + threadIdx.x) * 4;
  if (e0 + 3 < n_edges) {
    const int4 s4 = *(const int4*)&eidx[e0];
    const int4 t4 = *(const int4*)&eidx[n_edges + e0];
    const int4 y4 = *(const int4*)&etype[e0];
    int pos;
    pos = atomicAdd(&cursor[t4.x], 1);
    packed[pos] = (unsigned int)s4.x | ((unsigned int)y4.x << 17);
    pos = atomicAdd(&cursor[t4.y], 1);
    packed[pos] = (unsigned int)s4.y | ((unsigned int)y4.y << 17);
    pos = atomicAdd(&cursor[t4.z], 1);
    packed[pos] = (unsigned int)s4.z | ((unsigned int)y4.z << 17);
    pos = atomicAdd(&cursor[t4.w], 1);
    packed[pos] = (unsigned int)s4.w | ((unsigned int)y4.w << 17);
  } else {
    for (int e = e0; e < n_edges; ++e) {
      const int pos = atomicAdd(&cursor[eidx[n_edges + e]], 1);
      packed[pos] = (unsigned int)eidx[e] | ((unsigned int)etype[e] << 17);
    }
  }
}

// ================ aggregate: 2 nodes per wave, 4-deep pipeline =============
// out[n] = relu(h[n] + sum_{edges->n} (h[src] + em[etype])); h,em bf16.
// Lane covers 4 dims via uint2 (8B); invalid edges -> zero rows (L1-hot).
__global__ __launch_bounds__(256) void aggregate_kernel(
    const int* __restrict__ offsets, const unsigned int* __restrict__ packed,
    const uint2* __restrict__ e4, const uint2* __restrict__ h4,
    float* __restrict__ out, int n_nodes, int n_edges, unsigned int zero_p) {
  const int gid = blockIdx.x * 256 + threadIdx.x;
  const int lane = threadIdx.x & 63;
  const int half = lane >> 5;
  const int sl = lane & 31;
  const int n = (gid >> 6) * 2 + half;
  if (n >= n_nodes) return;

  const uint2 sb = h4[(size_t)n * 32 + sl];  // self (4 bf16)
  float a0 = bflo(sb.x), a1 = bfhi(sb.x), a2 = bflo(sb.y), a3 = bfhi(sb.y);
  float c0 = 0.f, c1 = 0.f, c2 = 0.f, c3 = 0.f;

  int j = offsets[n];
  const int end = offsets[n + 1];
  int trips = (end - j + 3) >> 2;
  int to = __shfl_xor(trips, 32);
  const int T = trips > to ? trips : to;
  const int emax = n_edges - 1;

  for (int t = 0; t < T; ++t, j += 4) {
    const int j1 = j + 1, j2 = j + 2, j3 = j + 3;
    unsigned int p0 = packed[j  <= emax ? j  : emax];
    unsigned int p1 = packed[j1 <= emax ? j1 : emax];
    unsigned int p2 = packed[j2 <= emax ? j2 : emax];
    unsigned int p3 = packed[j3 <= emax ? j3 : emax];
    p0 = (j  < end) ? p0 : zero_p;
    p1 = (j1 < end) ? p1 : zero_p;
    p2 = (j2 < end) ? p2 : zero_p;
    p3 = (j3 < end) ? p3 : zero_p;
    const uint2 g0 = h4[(size_t)(p0 & 0x1FFFFu) * 32 + sl];
    const uint2 g1 = h4[(size_t)(p1 & 0x1FFFFu) * 32 + sl];
    const uint2 g2 = h4[(size_t)(p2 & 0x1FFFFu) * 32 + sl];
    const uint2 g3 = h4[(size_t)(p3 & 0x1FFFFu) * 32 + sl];
    const uint2 e0 = e4[(p0 >> 17) * 32 + sl];
    const uint2 e1 = e4[(p1 >> 17) * 32 + sl];
    const uint2 e2 = e4[(p2 >> 17) * 32 + sl];
    const uint2 e3 = e4[(p3 >> 17) * 32 + sl];
    a0 += bflo(g0.x) + bflo(e0.x); a1 += bfhi(g0.x) + bfhi(e0.x);
    a2 += bflo(g0.y) + bflo(e0.y); a3 += bfhi(g0.y) + bfhi(e0.y);
    c0 += bflo(g1.x) + bflo(e1.x); c1 += bfhi(g1.x) + bfhi(e1.x);
    c2 += bflo(g1.y) + bflo(e1.y); c3 += bfhi(g1.y) + bfhi(e1.y);
    a0 += bflo(g2.x) + bflo(e2.x); a1 += bfhi(g2.x) + bfhi(e2.x);
    a2 += bflo(g2.y) + bflo(e2.y); a3 += bfhi(g2.y) + bfhi(e2.y);
    c0 += bflo(g3.x) + bflo(e3.x); c1 += bfhi(g3.x) + bfhi(e3.x);
    c2 += bflo(g3.y) + bflo(e3.y); c3 += bfhi(g3.y) + bfhi(e3.y);
  }

  float4 r;
  r.x = fmaxf(a0 + c0, 0.f);
  r.y = fmaxf(a1 + c1, 0.f);
  r.z = fmaxf(a2 + c2, 0.f);
  r.w = fmaxf(a3 + c3, 0.f);
  ((float4*)out)[(size_t)n * 32 + sl] = r;
}

// ===========================================================================
extern "C" void kernel_launch(void* const* d_in, const int* in_sizes, int n_in,
                              void* d_out, int out_size, void* d_ws,
                              size_t ws_size, hipStream_t stream) {
  const float* nf   = (const float*)d_in[0];  // (N, 128) f32
  const int*   eidx = (const int*)d_in[1];    // (2, E) int
  const int*   etyp = (const int*)d_in[2];    // (E,) int
  const float* eemb = (const float*)d_in[3];  // (64, 128) f32
  const float* W    = (const float*)d_in[4];  // (128, 128) f32
  const float* b    = (const float*)d_in[5];  // (128,) f32

  const int n_nodes = in_sizes[0] / D;  // 100000
  const int n_edges = in_sizes[2];      // 625000

  float* out = (float*)d_out;

  // workspace layout (~29.5 MB); 16B alignment maintained
  char* base = (char*)d_ws;
  unsigned short* Wt = (unsigned short*)base;                  // 32 KB
  unsigned short* em_bf = (unsigned short*)(base + 32768);     // 65 rows
  unsigned short* h_bf = (unsigned short*)(base + 65536);      // (N+1)*128 bf16
  char* tail = base + 65536 + (size_t)(n_nodes + 1) * D * 2;
  int* counts = (int*)tail;
  int* offsets = counts + n_nodes;
  int* cursor = offsets + (n_nodes + 1);
  int* blockSums = cursor + n_nodes;
  unsigned int* packed = (unsigned int*)(blockSums + 1024);    // E uints

  const int nb = (n_nodes + 1023) / 1024;        // 98 scan blocks (<=256)
  const int gemmBlocks = (n_nodes + 63) / 64;    // 1563
  const int epb = (n_edges + gemmBlocks - 1) / gemmBlocks;  // 400

  // 1) prep: Wt transpose+cast, em cast, zero counts + sentinel rows
  prep_kernel<<<(n_nodes + 255) / 256, 256, 0, stream>>>(W, eemb, Wt, em_bf,
                                                         h_bf, counts, n_nodes);

  // 2) GEMM h_bf = bf16(nf @ W + b) + fused histogram (LDS-free, pipelined)
  gemm_h_kernel<<<gemmBlocks, 256, 0, stream>>>(
      nf, Wt, b, h_bf, eidx + n_edges, counts, n_nodes, n_edges, epb);

  // 3) scan (2 kernels)
  scan1_kernel<<<nb, 256, 0, stream>>>(counts, offsets, blockSums, n_nodes);
  scan23_kernel<<<nb, 256, 0, stream>>>(offsets, cursor, blockSums, nb,
                                        n_nodes, n_edges);

  // 4) scatter packed (src|etype) by target
  scatter_kernel<<<(n_edges + 1023) / 1024, 256, 0, stream>>>(
      eidx, etyp, cursor, packed, n_edges);

  // 5) aggregate + self + ReLU (2 nodes/wave, 4-deep)
  const unsigned int zero_p = (unsigned int)n_nodes | (64u << 17);
  const int aggBlocks = (n_nodes + 7) / 8;  // 8 nodes per 256-thread block
  aggregate_kernel<<<aggBlocks, 256, 0, stream>>>(
      offsets, packed, (const uint2*)em_bf, (const uint2*)h_bf, out, n_nodes,
      n_edges, zero_p);
}

// Round 12
// 131.687 us; speedup vs baseline: 1.0753x; 1.0484x over previous
//
#include <hip/hip_runtime.h>
#include <hip/hip_bf16.h>

#define D 128          // D_IN == D_OUT == 128
#define GEMM_BLOCKS 768
#define HIST_BLOCKS 192

typedef __attribute__((ext_vector_type(8))) short short8v;   // 8 bf16 (4 VGPR)
typedef __attribute__((ext_vector_type(4))) float float4v;   // MFMA acc

__device__ __forceinline__ unsigned short f2bf(float f) {
  union { float f; unsigned int u; } v; v.f = f;
  unsigned int r = v.u + 0x7fffu + ((v.u >> 16) & 1u);  // RNE
  return (unsigned short)(r >> 16);
}
// packed pair conversion -> v_cvt_pk_bf16_f32 (RNE)
__device__ __forceinline__ unsigned int pkbf(float lo, float hi) {
  float2 f; f.x = lo; f.y = hi;
  __hip_bfloat162 v = __float22bfloat162_rn(f);
  union { __hip_bfloat162 b; unsigned int u; } c; c.b = v;
  return c.u;
}
__device__ __forceinline__ float bflo(unsigned int u) {
  union { unsigned int v; float f; } c; c.v = u << 16; return c.f;
}
__device__ __forceinline__ float bfhi(unsigned int u) {
  union { unsigned int v; float f; } c; c.v = u & 0xffff0000u; return c.f;
}

// == prep: Wt[n][k]=bf16(W[k][n]); em_bf=bf16(eemb); zero counts+sentinels ==
__global__ __launch_bounds__(256) void prep_kernel(
    const float* __restrict__ W, const float* __restrict__ eemb,
    unsigned short* __restrict__ Wt, unsigned short* __restrict__ em_bf,
    unsigned short* __restrict__ h_bf, int* __restrict__ counts,
    int n_nodes) {
  int i = blockIdx.x * 256 + threadIdx.x;
  if (i < D * D) Wt[i] = f2bf(W[(i & 127) * D + (i >> 7)]);      // transpose
  if (i < 64 * D) em_bf[i] = f2bf(eemb[i]);
  if (i < 64) ((unsigned int*)(h_bf + (size_t)n_nodes * D))[i] = 0u;
  if (i >= 64 && i < 128) ((unsigned int*)(em_bf + 64 * D))[i - 64] = 0u;
  if (i < n_nodes) counts[i] = 0;
}

// ============ GEMM: persistent waves + resident A-frags + hist blocks ======
// Blocks [0, GEMM_BLOCKS): 4 waves each; wave-pair p covers 16-node tiles
// p, p+1536, ...; within a pair, ch=0/1 waves own col-halves [0,64)/[64,128).
// A-frags (wave's 64 Wt cols, 64 VGPR) loaded ONCE, live across the loop;
// x-loads for tile t+1 land in the other named array (2-body unrolled loop)
// so 8 loads stay in flight across each COMPUTE.
// Blocks [GEMM_BLOCKS, +HIST_BLOCKS): edge-target histogram only (concurrent).
__device__ __forceinline__ void loadx(const float* __restrict__ nf, int t,
                                      int m, int q, float4 (&xr)[8]) {
  const float4* xr4 = (const float4*)(nf + (size_t)(t * 16 + m) * D);
  #pragma unroll
  for (int kc = 0; kc < 4; ++kc) {
    xr[kc * 2]     = xr4[kc * 8 + q * 2];
    xr[kc * 2 + 1] = xr4[kc * 8 + q * 2 + 1];
  }
}

__device__ __forceinline__ void compute_store(
    const float4 (&xr)[8], const short8v (&A)[4][4],
    const float* __restrict__ b, unsigned short* __restrict__ h_bf,
    int t, int m, int q, int ch) {
  short8v bf[4];
  #pragma unroll
  for (int kc = 0; kc < 4; ++kc) {
    union { unsigned int u[4]; short8v s; } cv;
    cv.u[0] = pkbf(xr[kc * 2].x, xr[kc * 2].y);
    cv.u[1] = pkbf(xr[kc * 2].z, xr[kc * 2].w);
    cv.u[2] = pkbf(xr[kc * 2 + 1].x, xr[kc * 2 + 1].y);
    cv.u[3] = pkbf(xr[kc * 2 + 1].z, xr[kc * 2 + 1].w);
    bf[kc] = cv.s;
  }
  float4v acc[4] = {};
  #pragma unroll
  for (int kc = 0; kc < 4; ++kc) {
    #pragma unroll
    for (int nt = 0; nt < 4; ++nt)
      acc[nt] = __builtin_amdgcn_mfma_f32_16x16x32_bf16(A[nt][kc], bf[kc],
                                                        acc[nt], 0, 0, 0);
  }
  unsigned short* orow = h_bf + (size_t)(t * 16 + m) * D + ch * 64 + q * 4;
  #pragma unroll
  for (int nt = 0; nt < 4; ++nt) {
    const float4 bv = *(const float4*)(b + ch * 64 + nt * 16 + q * 4);
    uint2 val;
    val.x = pkbf(acc[nt][0] + bv.x, acc[nt][1] + bv.y);
    val.y = pkbf(acc[nt][2] + bv.z, acc[nt][3] + bv.w);
    *(uint2*)(orow + nt * 16) = val;
  }
}

__global__ __launch_bounds__(256, 2) void gemm_h_kernel(
    const float* __restrict__ nf, const unsigned short* __restrict__ Wt,
    const float* __restrict__ b, unsigned short* __restrict__ h_bf,
    const int* __restrict__ eidx_tgt, int* __restrict__ counts,
    int n_edges, int n_tiles) {
  const int tid = threadIdx.x;

  if (blockIdx.x >= GEMM_BLOCKS) {  // -------- histogram-only blocks --------
    const int nthr = HIST_BLOCKS * 256;
    for (int e = (blockIdx.x - GEMM_BLOCKS) * 256 + tid; e < n_edges;
         e += nthr)
      atomicAdd(&counts[eidx_tgt[e]], 1);
    return;
  }

  const int wv = tid >> 6, ln = tid & 63;
  const int m = ln & 15, q = ln >> 4;
  const int wgl = blockIdx.x * 4 + wv;   // 0..3071
  const int pair = wgl >> 1;             // 0..1535
  const int ch = wgl & 1;                // col-half
  const int nPairs = GEMM_BLOCKS * 2;    // 1536

  // ---- A fragments: this wave's 64 Wt columns, resident for all tiles ----
  short8v A[4][4];  // [nt][kc] = 64 VGPR
  #pragma unroll
  for (int nt = 0; nt < 4; ++nt) {
    const unsigned short* wrow = Wt + (ch * 64 + nt * 16 + m) * D + q * 8;
    #pragma unroll
    for (int kc = 0; kc < 4; ++kc)
      A[nt][kc] = *(const short8v*)(wrow + kc * 32);
  }

  float4 xa[8], xb[8];

  int t = pair;
  if (t >= n_tiles) return;
  loadx(nf, t, m, q, xa);
  while (true) {
    const int t2 = t + nPairs;
    if (t2 < n_tiles) loadx(nf, t2, m, q, xb);
    compute_store(xa, A, b, h_bf, t, m, q, ch);
    if (t2 >= n_tiles) break;
    t = t2;
    const int t3 = t + nPairs;
    if (t3 < n_tiles) loadx(nf, t3, m, q, xa);
    compute_store(xb, A, b, h_bf, t, m, q, ch);
    if (t3 >= n_tiles) break;
    t = t3;
  }
}

// ============================ scan =========================================
__global__ __launch_bounds__(256) void scan1_kernel(
    const int* __restrict__ counts, int* __restrict__ offsets,
    int* __restrict__ blockSums, int n) {
  __shared__ int lds[256];
  const int tid = threadIdx.x;
  const int base = blockIdx.x * 1024 + tid * 4;
  int v[4];
  #pragma unroll
  for (int k = 0; k < 4; ++k) v[k] = (base + k < n) ? counts[base + k] : 0;
  int s = v[0] + v[1] + v[2] + v[3];
  lds[tid] = s;
  for (int off = 1; off < 256; off <<= 1) {
    __syncthreads();
    int t = (tid >= off) ? lds[tid - off] : 0;
    __syncthreads();
    lds[tid] += t;
  }
  __syncthreads();
  int run = lds[tid] - s;
  #pragma unroll
  for (int k = 0; k < 4; ++k) {
    if (base + k < n) offsets[base + k] = run;
    run += v[k];
  }
  if (tid == 255) blockSums[blockIdx.x] = lds[255];
}

__global__ __launch_bounds__(256) void scan23_kernel(
    int* __restrict__ offsets, int* __restrict__ cursor,
    const int* __restrict__ blockSums, int nb, int n, int n_edges) {
  __shared__ int lds[256];
  const int tid = threadIdx.x;
  const int bid = blockIdx.x;
  lds[tid] = (tid < bid && tid < nb) ? blockSums[tid] : 0;
  __syncthreads();
  #pragma unroll
  for (int off = 128; off > 0; off >>= 1) {
    if (tid < off) lds[tid] += lds[tid + off];
    __syncthreads();
  }
  const int add = lds[0];
  const int base = bid * 1024 + tid * 4;
  #pragma unroll
  for (int k = 0; k < 4; ++k) {
    int i = base + k;
    if (i < n) {
      int o = offsets[i] + add;
      offsets[i] = o;
      cursor[i] = o;
    }
  }
  if (bid == 0 && tid == 0) offsets[n] = n_edges;
}

// ================== scatter: 4 edges/thread via int4 =======================
__global__ __launch_bounds__(256) void scatter_kernel(
    const int* __restrict__ eidx, const int* __restrict__ etype,
    int* __restrict__ cursor, unsigned int* __restrict__ packed, int n_edges) {
  const int e0 = (blockIdx.x * 256 + threadIdx.x) * 4;
  if (e0 + 3 < n_edges) {
    const int4 s4 = *(const int4*)&eidx[e0];
    const int4 t4 = *(const int4*)&eidx[n_edges + e0];
    const int4 y4 = *(const int4*)&etype[e0];
    int pos;
    pos = atomicAdd(&cursor[t4.x], 1);
    packed[pos] = (unsigned int)s4.x | ((unsigned int)y4.x << 17);
    pos = atomicAdd(&cursor[t4.y], 1);
    packed[pos] = (unsigned int)s4.y | ((unsigned int)y4.y << 17);
    pos = atomicAdd(&cursor[t4.z], 1);
    packed[pos] = (unsigned int)s4.z | ((unsigned int)y4.z << 17);
    pos = atomicAdd(&cursor[t4.w], 1);
    packed[pos] = (unsigned int)s4.w | ((unsigned int)y4.w << 17);
  } else {
    for (int e = e0; e < n_edges; ++e) {
      const int pos = atomicAdd(&cursor[eidx[n_edges + e]], 1);
      packed[pos] = (unsigned int)eidx[e] | ((unsigned int)etype[e] << 17);
    }
  }
}

// ================ aggregate: 2 nodes per wave, 4-deep pipeline =============
__global__ __launch_bounds__(256) void aggregate_kernel(
    const int* __restrict__ offsets, const unsigned int* __restrict__ packed,
    const uint2* __restrict__ e4, const uint2* __restrict__ h4,
    float* __restrict__ out, int n_nodes, int n_edges, unsigned int zero_p) {
  const int gid = blockIdx.x * 256 + threadIdx.x;
  const int lane = threadIdx.x & 63;
  const int half = lane >> 5;
  const int sl = lane & 31;
  const int n = (gid >> 6) * 2 + half;
  if (n >= n_nodes) return;

  const uint2 sb = h4[(size_t)n * 32 + sl];  // self (4 bf16)
  float a0 = bflo(sb.x), a1 = bfhi(sb.x), a2 = bflo(sb.y), a3 = bfhi(sb.y);
  float c0 = 0.f, c1 = 0.f, c2 = 0.f, c3 = 0.f;

  int j = offsets[n];
  const int end = offsets[n + 1];
  int trips = (end - j + 3) >> 2;
  int to = __shfl_xor(trips, 32);
  const int T = trips > to ? trips : to;
  const int emax = n_edges - 1;

  for (int t = 0; t < T; ++t, j += 4) {
    const int j1 = j + 1, j2 = j + 2, j3 = j + 3;
    unsigned int p0 = packed[j  <= emax ? j  : emax];
    unsigned int p1 = packed[j1 <= emax ? j1 : emax];
    unsigned int p2 = packed[j2 <= emax ? j2 : emax];
    unsigned int p3 = packed[j3 <= emax ? j3 : emax];
    p0 = (j  < end) ? p0 : zero_p;
    p1 = (j1 < end) ? p1 : zero_p;
    p2 = (j2 < end) ? p2 : zero_p;
    p3 = (j3 < end) ? p3 : zero_p;
    const uint2 g0 = h4[(size_t)(p0 & 0x1FFFFu) * 32 + sl];
    const uint2 g1 = h4[(size_t)(p1 & 0x1FFFFu) * 32 + sl];
    const uint2 g2 = h4[(size_t)(p2 & 0x1FFFFu) * 32 + sl];
    const uint2 g3 = h4[(size_t)(p3 & 0x1FFFFu) * 32 + sl];
    const uint2 e0 = e4[(p0 >> 17) * 32 + sl];
    const uint2 e1 = e4[(p1 >> 17) * 32 + sl];
    const uint2 e2 = e4[(p2 >> 17) * 32 + sl];
    const uint2 e3 = e4[(p3 >> 17) * 32 + sl];
    a0 += bflo(g0.x) + bflo(e0.x); a1 += bfhi(g0.x) + bfhi(e0.x);
    a2 += bflo(g0.y) + bflo(e0.y); a3 += bfhi(g0.y) + bfhi(e0.y);
    c0 += bflo(g1.x) + bflo(e1.x); c1 += bfhi(g1.x) + bfhi(e1.x);
    c2 += bflo(g1.y) + bflo(e1.y); c3 += bfhi(g1.y) + bfhi(e1.y);
    a0 += bflo(g2.x) + bflo(e2.x); a1 += bfhi(g2.x) + bfhi(e2.x);
    a2 += bflo(g2.y) + bflo(e2.y); a3 += bfhi(g2.y) + bfhi(e2.y);
    c0 += bflo(g3.x) + bflo(e3.x); c1 += bfhi(g3.x) + bfhi(e3.x);
    c2 += bflo(g3.y) + bflo(e3.y); c3 += bfhi(g3.y) + bfhi(e3.y);
  }

  float4 r;
  r.x = fmaxf(a0 + c0, 0.f);
  r.y = fmaxf(a1 + c1, 0.f);
  r.z = fmaxf(a2 + c2, 0.f);
  r.w = fmaxf(a3 + c3, 0.f);
  ((float4*)out)[(size_t)n * 32 + sl] = r;
}

// ===========================================================================
extern "C" void kernel_launch(void* const* d_in, const int* in_sizes, int n_in,
                              void* d_out, int out_size, void* d_ws,
                              size_t ws_size, hipStream_t stream) {
  const float* nf   = (const float*)d_in[0];  // (N, 128) f32
  const int*   eidx = (const int*)d_in[1];    // (2, E) int
  const int*   etyp = (const int*)d_in[2];    // (E,) int
  const float* eemb = (const float*)d_in[3];  // (64, 128) f32
  const float* W    = (const float*)d_in[4];  // (128, 128) f32
  const float* b    = (const float*)d_in[5];  // (128,) f32

  const int n_nodes = in_sizes[0] / D;  // 100000
  const int n_edges = in_sizes[2];      // 625000

  float* out = (float*)d_out;

  // workspace layout (~29.5 MB); 16B alignment maintained
  char* base = (char*)d_ws;
  unsigned short* Wt = (unsigned short*)base;                  // 32 KB
  unsigned short* em_bf = (unsigned short*)(base + 32768);     // 65 rows
  unsigned short* h_bf = (unsigned short*)(base + 65536);      // (N+1)*128 bf16
  char* tail = base + 65536 + (size_t)(n_nodes + 1) * D * 2;
  int* counts = (int*)tail;
  int* offsets = counts + n_nodes;
  int* cursor = offsets + (n_nodes + 1);
  int* blockSums = cursor + n_nodes;
  unsigned int* packed = (unsigned int*)(blockSums + 1024);    // E uints

  const int nb = (n_nodes + 1023) / 1024;        // 98 scan blocks (<=256)
  const int n_tiles = (n_nodes + 15) / 16;       // 6250

  // 1) prep: Wt transpose+cast, em cast, zero counts + sentinel rows
  prep_kernel<<<(n_nodes + 255) / 256, 256, 0, stream>>>(W, eemb, Wt, em_bf,
                                                         h_bf, counts, n_nodes);

  // 2) GEMM (persistent waves) + histogram (dedicated blocks, concurrent)
  gemm_h_kernel<<<GEMM_BLOCKS + HIST_BLOCKS, 256, 0, stream>>>(
      nf, Wt, b, h_bf, eidx + n_edges, counts, n_edges, n_tiles);

  // 3) scan (2 kernels)
  scan1_kernel<<<nb, 256, 0, stream>>>(counts, offsets, blockSums, n_nodes);
  scan23_kernel<<<nb, 256, 0, stream>>>(offsets, cursor, blockSums, nb,
                                        n_nodes, n_edges);

  // 4) scatter packed (src|etype) by target
  scatter_kernel<<<(n_edges + 1023) / 1024, 256, 0, stream>>>(
      eidx, etyp, cursor, packed, n_edges);

  // 5) aggregate + self + ReLU (2 nodes/wave, 4-deep)
  const unsigned int zero_p = (unsigned int)n_nodes | (64u << 17);
  const int aggBlocks = (n_nodes + 7) / 8;
  aggregate_kernel<<<aggBlocks, 256, 0, stream>>>(
      offsets, packed, (const uint2*)em_bf, (const uint2*)h_bf, out, n_nodes,
      n_edges, zero_p);
}